// Round 1
// baseline (442.075 us; speedup 1.0000x reference)
//
#include <hip/hip_runtime.h>

// SCF GRU layer: T=40 steps, B=128 batches, N=64 agents/batch, H=48 hidden.
// BN = 8192 rows. DIN = 52 = loc(2) + rel(2) + vel(16) + img_feat(32).
//
// Decomposition:
//  k_img_mean : img_feat[b][c] = mean over 80x80 of f_img          (HBM-bound, 105 MB)
//  k_ssum     : S[t][b][2]     = sum of locs over the 64 agents    (tiny)
//  k_g0       : G0[b][g]       = b_ih[g] + img_feat[b] . W_ih[g,20:52]  (time-invariant gi part)
//  k_gru      : per-row independent 40-step recurrence. 96 threads/row:
//               thread = (gate j in [0,48), half in {0,1} of K-range).
//               Weights live in registers (float2 pairs -> v_pk_fma_f32),
//               h lives in LDS (broadcast reads), partials combined via shfl_xor(1).

#define T_STEPS 40
#define BB      128
#define NN      64
#define HH      48
#define BN      8192
#define G3      144   // 3*H

__device__ __forceinline__ float sigmoid_(float x) {
    return __builtin_amdgcn_rcpf(1.0f + __expf(-x));
}

__global__ __launch_bounds__(256) void k_img_mean(const float* __restrict__ f_img,
                                                  float* __restrict__ img_out) {
    const int bc = blockIdx.x;  // 0..4095 = b*32+c
    const float4* p = reinterpret_cast<const float4*>(f_img + (size_t)bc * 6400);
    float s = 0.0f;
    for (int i = threadIdx.x; i < 1600; i += 256) {
        float4 v = p[i];
        s += v.x + v.y + v.z + v.w;
    }
    for (int off = 32; off > 0; off >>= 1) s += __shfl_down(s, off, 64);
    __shared__ float red[4];
    const int wid = threadIdx.x >> 6, lane = threadIdx.x & 63;
    if (lane == 0) red[wid] = s;
    __syncthreads();
    if (threadIdx.x == 0)
        img_out[bc] = (red[0] + red[1] + red[2] + red[3]) * (1.0f / 6400.0f);
}

__global__ __launch_bounds__(64) void k_ssum(const float* __restrict__ path,
                                             float* __restrict__ S) {
    const int tb = blockIdx.x;  // t*128 + b   (t*8192 + b*64 == tb*64)
    const float2 v = reinterpret_cast<const float2*>(path)[(size_t)tb * 64 + threadIdx.x];
    float sx = v.x, sy = v.y;
    for (int off = 32; off > 0; off >>= 1) {
        sx += __shfl_down(sx, off, 64);
        sy += __shfl_down(sy, off, 64);
    }
    if (threadIdx.x == 0) { S[tb * 2] = sx; S[tb * 2 + 1] = sy; }
}

__global__ __launch_bounds__(256) void k_g0(const float* __restrict__ img,
                                            const float* __restrict__ W_ih,
                                            const float* __restrict__ b_ih,
                                            float* __restrict__ G0) {
    const int id = blockIdx.x * 256 + threadIdx.x;
    if (id >= BB * G3) return;
    const int b = id / G3, g = id % G3;
    float acc = b_ih[g];
    const float* w = W_ih + g * 52 + 20;
    const float* im = img + b * 32;
#pragma unroll
    for (int c = 0; c < 32; ++c) acc = fmaf(im[c], w[c], acc);
    G0[id] = acc;
}

// Main recurrence. Block = 192 threads = 2 rows x 96 threads.
// Within a row: lane q = j*2 + half, so shfl_xor(1) pairs the two K-halves.
__global__ __launch_bounds__(192) void k_gru(const float* __restrict__ path,
                                             const float* __restrict__ f_vel,
                                             const float* __restrict__ W_ih,
                                             const float* __restrict__ W_hh,
                                             const float* __restrict__ b_hh,
                                             const float* __restrict__ G0,
                                             const float* __restrict__ S,
                                             float* __restrict__ out) {
    const int tid  = threadIdx.x;
    const int r    = tid / 96;       // row slot within block
    const int q    = tid % 96;
    const int j    = q >> 1;         // gate/hidden index 0..47
    const int half = q & 1;          // K-range half
    const int row  = blockIdx.x * 2 + r;
    const int b    = row >> 6;       // batch = row / 64

    __shared__ float sh[2][HH];      // hidden state per row
    __shared__ float sx[2][20];      // time-varying input [loc(2), rel(2), vel(16)]

    // ---- weights into registers (float2 pairs -> packed fp32 FMA) ----
    float2 wihr[5], wihz[5], wihn[5];      // x-part, K-half = 10 floats
    float2 whhr[12], whhz[12], whhn[12];   // h-part, K-half = 24 floats
    {
        const float2* wr = reinterpret_cast<const float2*>(W_ih + (j)      * 52 + half * 10);
        const float2* wz = reinterpret_cast<const float2*>(W_ih + (48 + j) * 52 + half * 10);
        const float2* wn = reinterpret_cast<const float2*>(W_ih + (96 + j) * 52 + half * 10);
#pragma unroll
        for (int p = 0; p < 5; ++p) { wihr[p] = wr[p]; wihz[p] = wz[p]; wihn[p] = wn[p]; }
    }
    {
        const float2* wr = reinterpret_cast<const float2*>(W_hh + (j)      * 48 + half * 24);
        const float2* wz = reinterpret_cast<const float2*>(W_hh + (48 + j) * 48 + half * 24);
        const float2* wn = reinterpret_cast<const float2*>(W_hh + (96 + j) * 48 + half * 24);
#pragma unroll
        for (int p = 0; p < 12; ++p) { whhr[p] = wr[p]; whhz[p] = wz[p]; whhn[p] = wn[p]; }
    }
    const float g0r = G0[b * G3 + j];
    const float g0z = G0[b * G3 + 48 + j];
    const float g0n = G0[b * G3 + 96 + j];
    const float bhr = b_hh[j], bhz = b_hh[48 + j], bhn = b_hh[96 + j];

    if (half == 0) sh[r][j] = 0.0f;  // h0 = 0
    __syncthreads();

    const float2* sh2 = reinterpret_cast<const float2*>(sh[r]);
    const float2* sx2 = reinterpret_cast<const float2*>(sx[r]);

    for (int t = 0; t < T_STEPS; ++t) {
        // ---- stage x[t] for this row into LDS ----
        if (q < 16) {
            sx[r][4 + q] = f_vel[((size_t)t * BN + row) * 16 + q];
        } else if (q == 16) {
            const float2 l = reinterpret_cast<const float2*>(path)[(size_t)t * BN + row];
            const int tb = t * BB + b;
            const float Sx = S[tb * 2], Sy = S[tb * 2 + 1];
            sx[r][0] = l.x;
            sx[r][1] = l.y;
            sx[r][2] = (Sx - 64.0f * l.x) * (1.0f / 63.0f);  // rel = (S - 64*loc)/63
            sx[r][3] = (Sy - 64.0f * l.y) * (1.0f / 63.0f);
        }
        __syncthreads();

        float2 ar  = {0.0f, 0.0f};   // r-gate: i + h combined
        float2 az  = {0.0f, 0.0f};   // z-gate: i + h combined
        float2 ani = {0.0f, 0.0f};   // n-gate input part
        float2 anh = {0.0f, 0.0f};   // n-gate hidden part (r multiplies this)
#pragma unroll
        for (int p = 0; p < 5; ++p) {
            const float2 xv = sx2[half * 5 + p];
            ar.x  = fmaf(xv.x, wihr[p].x, ar.x);  ar.y  = fmaf(xv.y, wihr[p].y, ar.y);
            az.x  = fmaf(xv.x, wihz[p].x, az.x);  az.y  = fmaf(xv.y, wihz[p].y, az.y);
            ani.x = fmaf(xv.x, wihn[p].x, ani.x); ani.y = fmaf(xv.y, wihn[p].y, ani.y);
        }
#pragma unroll
        for (int p = 0; p < 12; ++p) {
            const float2 hv = sh2[half * 12 + p];
            ar.x  = fmaf(hv.x, whhr[p].x, ar.x);  ar.y  = fmaf(hv.y, whhr[p].y, ar.y);
            az.x  = fmaf(hv.x, whhz[p].x, az.x);  az.y  = fmaf(hv.y, whhz[p].y, az.y);
            anh.x = fmaf(hv.x, whhn[p].x, anh.x); anh.y = fmaf(hv.y, whhn[p].y, anh.y);
        }
        float sr  = ar.x + ar.y;   sr  += __shfl_xor(sr, 1, 64);
        float szv = az.x + az.y;   szv += __shfl_xor(szv, 1, 64);
        float sni = ani.x + ani.y; sni += __shfl_xor(sni, 1, 64);
        float snh = anh.x + anh.y; snh += __shfl_xor(snh, 1, 64);

        const float rg = sigmoid_(sr + g0r + bhr);
        const float zg = sigmoid_(szv + g0z + bhz);
        float a = (sni + g0n) + rg * (snh + bhn);   // b_hh inside r*h_n (not folded into G0)
        a = fminf(fmaxf(a, -15.0f), 15.0f);
        const float e = __expf(-2.0f * a);
        const float cand = (1.0f - e) * __builtin_amdgcn_rcpf(1.0f + e);
        const float hp = sh[r][j];
        const float hn = zg * (hp - cand) + cand;   // (1-z)*cand + z*h

        __syncthreads();  // all reads of sh/sx for step t complete
        if (half == 0) {
            sh[r][j] = hn;
        } else {
            out[((size_t)t * BN + row) * HH + j] = hn;
            if (t == T_STEPS - 1)
                out[(size_t)T_STEPS * BN * HH + (size_t)row * HH + j] = hn;  // hT
        }
        // loop-top barrier (after next x-stage) makes sh write visible before reads
    }
}

extern "C" void kernel_launch(void* const* d_in, const int* in_sizes, int n_in,
                              void* d_out, int out_size, void* d_ws, size_t ws_size,
                              hipStream_t stream) {
    const float* path  = (const float*)d_in[0];
    const float* f_vel = (const float*)d_in[1];
    const float* f_img = (const float*)d_in[2];
    const float* W_ih  = (const float*)d_in[3];
    const float* W_hh  = (const float*)d_in[4];
    const float* b_ih  = (const float*)d_in[5];
    const float* b_hh  = (const float*)d_in[6];
    float* out = (float*)d_out;

    float* ws  = (float*)d_ws;
    float* img = ws;                  // 4096 floats
    float* G0  = ws + 4096;           // 18432 floats
    float* S   = ws + 4096 + 18432;   // 10240 floats

    hipLaunchKernelGGL(k_img_mean, dim3(4096), dim3(256), 0, stream, f_img, img);
    hipLaunchKernelGGL(k_ssum, dim3(T_STEPS * BB), dim3(64), 0, stream, path, S);
    hipLaunchKernelGGL(k_g0, dim3((BB * G3 + 255) / 256), dim3(256), 0, stream,
                       img, W_ih, b_ih, G0);
    hipLaunchKernelGGL(k_gru, dim3(BN / 2), dim3(192), 0, stream,
                       path, f_vel, W_ih, W_hh, b_hh, G0, S, out);
}